// Round 1
// 124.725 us; speedup vs baseline: 1.1201x; 1.1201x over previous
//
#include <hip/hip_runtime.h>

typedef __attribute__((ext_vector_type(8))) short s16x8;
typedef __attribute__((ext_vector_type(4))) short s16x4;
typedef __attribute__((ext_vector_type(4))) float f32x4;

namespace {
constexpr int kCS = 256, kDH = 64, kDS = 128, kBH = 512;
constexpr float kAlpha = 0.5f;

// LDS byte offsets (total 30 KB -> 5 blocks/CU, 20 waves/CU)
constexpr int OFF_AC   = 0;                  // ac: 256 f32
constexpr int OFF_ENEG = 1024;               // eneg: 256 f32
constexpr int OFF_B    = 2048;               // Bhi [32][128] s16 (8KB); aliased by C fp32 bounce (16KB) and HThi half
constexpr int OFF_BLO  = OFF_B + 8192;       // Blo / HTlo
constexpr int OFF_XT   = OFF_B + 16384;      // XThi [64][32] s16 (4KB)
constexpr int OFF_XTLO = OFF_XT + 4096;      // XTlo
constexpr int OFF_S    = OFF_XTLO + 4096;    // S~hi per-wave [16][32] s16, 4 waves (4KB); cumsum partials early
constexpr int LDS_BYTES = OFF_S + 4096;      // 30720
}

union F4 { float4 v; float f[4]; };

__device__ __forceinline__ unsigned short bf16rn(float x) {
  unsigned u = __float_as_uint(x);
  u += 0x7FFFu + ((u >> 16) & 1u);
  return (unsigned short)(u >> 16);
}

__device__ __forceinline__ void split8(const float* v, s16x8& hi, s16x8& lo) {
#pragma unroll
  for (int i = 0; i < 8; ++i) {
    unsigned short h = bf16rn(v[i]);
    float hf = __uint_as_float((unsigned)h << 16);
    hi[i] = (short)h;
    lo[i] = (short)bf16rn(v[i] - hf);
  }
}

// LDS ping-pong scan for hend_kernel (unchanged path)
__device__ __forceinline__ void cumsum256(const float* __restrict__ Ab, float* ac, int tid) {
  ac[tid] = Ab[tid];
  __syncthreads();
  for (int off = 1; off < kCS; off <<= 1) {
    float v = ac[tid];
    if (tid >= off) v += ac[tid - off];
    __syncthreads();
    ac[tid] = v;
    __syncthreads();
  }
}

// Y[i,d] = (1-a)*sum_{j<=i} exp(ac_i-ac_j)*CB[i,j]*X[j,d] + a*exp(ac_i)*(C·h_prev)[i,d]
__global__ __launch_bounds__(256, 5) void y_mfma_kernel(
    const float* __restrict__ Xg, const float* __restrict__ Ag,
    const float* __restrict__ Bg, const float* __restrict__ Cg,
    const float* __restrict__ Hg, float* __restrict__ Yg) {
  __shared__ __align__(16) char smem[LDS_BYTES];
  float* ac   = (float*)(smem + OFF_AC);
  float* eneg = (float*)(smem + OFF_ENEG);
  short* Bhi  = (short*)(smem + OFF_B);
  short* Blo  = (short*)(smem + OFF_BLO);
  short* XThi = (short*)(smem + OFF_XT);
  short* XTlo = (short*)(smem + OFF_XTLO);
  short* Sall = (short*)(smem + OFF_S);
  float* Cb   = (float*)(smem + OFF_B);   // fp32 bounce, aliases Bhi+Blo (16KB)
  short* HThi = Bhi;                      // h_prev^T half-planes alias B planes
  short* HTlo = Blo;

  const int bidx = blockIdx.x;
  const int it = 3 - (bidx >> 9);   // heavy tiles dispatched first
  const int bh = bidx & 511;
  const int tid = threadIdx.x;
  const int lane = tid & 63;
  const int w = tid >> 6;
  const int fr = lane & 15;   // fragment free-index (A row / B col / D col)
  const int fg = lane >> 4;   // fragment k-group

  const float* Xb = Xg + (size_t)bh * kCS * kDH;
  const float* Ab = Ag + (size_t)bh * kCS;
  const float* Bb = Bg + (size_t)bh * kCS * kDS;
  const float* Cg_b = Cg + (size_t)bh * kCS * kDS;
  const float* Hb = Hg + (size_t)bh * kDS * kDH;
  float* Yb = Yg + (size_t)bh * kCS * kDH;

  // ---- cumsum via wave shuffle scan (2 barriers instead of 16)
  {
    float v = Ab[tid];
#pragma unroll
    for (int off = 1; off < 64; off <<= 1) {
      float t = __shfl_up(v, off);
      if (lane >= off) v += t;
    }
    float* wsum = (float*)(smem + OFF_S);
    if (lane == 63) wsum[w] = v;
    __syncthreads();
    float base = 0.f;
#pragma unroll
    for (int k = 0; k < 4; ++k)
      if (k < w) base += wsum[k];
    const float a = v + base;
    ac[tid] = a;
    eneg[tid] = __expf(-a);
    __syncthreads();
  }

  const int i0 = it * 64;
  float eaci[4];
#pragma unroll
  for (int r = 0; r < 4; ++r) eaci[r] = __expf(ac[i0 + w * 16 + fg * 4 + r]);

  // ---- C bounce in two 32-row halves: global (coalesced) -> LDS fp32 (16B-block XOR swizzle)
  s16x8 chi[4], clo[4];
#pragma unroll
  for (int m = 0; m < 2; ++m) {
#pragma unroll
    for (int k = 0; k < 4; ++k) {
      int fid = k * 256 + tid;
      int r = fid >> 5, c = fid & 31;
      *(float4*)&Cb[r * 128 + ((c ^ (r & 7)) << 2)] =
          *(const float4*)&Cg_b[(size_t)(i0 + m * 32 + r) * kDS + c * 4];
    }
    __syncthreads();
    if ((w >> 1) == m) {
      const int lrow = (w & 1) * 16 + fr;
      const float* crow = &Cb[lrow * 128];
      const int r7 = lrow & 7;
#pragma unroll
      for (int kc = 0; kc < 4; ++kc) {
        const int c0 = kc * 8 + fg * 2;
        F4 u0, u1;
        u0.v = *(const float4*)&crow[(c0 ^ r7) << 2];
        u1.v = *(const float4*)&crow[((c0 + 1) ^ r7) << 2];
        float v[8] = {u0.f[0], u0.f[1], u0.f[2], u0.f[3], u1.f[0], u1.f[1], u1.f[2], u1.f[3]};
        split8(v, chi[kc], clo[kc]);
      }
    }
    __syncthreads();
  }

  f32x4 yacc[4];
#pragma unroll
  for (int n = 0; n < 4; ++n)
#pragma unroll
    for (int r = 0; r < 4; ++r) yacc[n][r] = 0.f;

  short* Sp = Sall + w * 512;  // per-wave S~ plane [16][32]

  const int jt_n = 2 * it + 2;
  for (int jt = 0; jt < jt_n; ++jt) {
    const int j0 = jt * 32;
    // ---- stage B tile [32][128] fp32 -> hi/lo planes, 16B-granule XOR swizzle
#pragma unroll
    for (int k = 0; k < 2; ++k) {
      const int row = k * 16 + (tid >> 4);
      const int g = tid & 15;
      F4 u0, u1;
      u0.v = *(const float4*)&Bb[(size_t)(j0 + row) * kDS + g * 8];
      u1.v = *(const float4*)&Bb[(size_t)(j0 + row) * kDS + g * 8 + 4];
      float v[8] = {u0.f[0], u0.f[1], u0.f[2], u0.f[3], u1.f[0], u1.f[1], u1.f[2], u1.f[3]};
      s16x8 h8, l8;
      split8(v, h8, l8);
      const int col = (g ^ (row & 7)) * 8;
      *(s16x8*)&Bhi[row * 128 + col] = h8;
      *(s16x8*)&Blo[row * 128 + col] = l8;
    }
    // ---- stage X^T tile: X[32t][64d] -> XT[d][t] hi/lo; wave w owns t-block w
    {
      const int d = lane;
      float xv[8];
#pragma unroll
      for (int s = 0; s < 8; ++s)
        xv[s] = Xb[(size_t)(j0 + w * 8 + s) * kDH + d];
      s16x8 h8, l8;
      split8(xv, h8, l8);
      const int off = d * 32 + ((w ^ ((d >> 2) & 3)) << 3);
      *(s16x8*)&XThi[off] = h8;
      *(s16x8*)&XTlo[off] = l8;
    }
    __syncthreads();

    // ---- S = C·B^T  (split: Chi·Bhi + Chi·Blo + Clo·Bhi)
    f32x4 s[2];
#pragma unroll
    for (int n = 0; n < 2; ++n) {
#pragma unroll
      for (int r = 0; r < 4; ++r) s[n][r] = 0.f;
      const int jrow = n * 16 + fr;
      const short* bph = &Bhi[jrow * 128];
      const short* bpl = &Blo[jrow * 128];
#pragma unroll
      for (int kc = 0; kc < 4; ++kc) {
        const int phys = ((4 * kc + fg) ^ (jrow & 7)) * 8;
        s16x8 b8 = *(const s16x8*)&bph[phys];
        s16x8 l8 = *(const s16x8*)&bpl[phys];
        s[n] = __builtin_amdgcn_mfma_f32_16x16x32_bf16(chi[kc], b8, s[n], 0, 0, 0);
        s[n] = __builtin_amdgcn_mfma_f32_16x16x32_bf16(chi[kc], l8, s[n], 0, 0, 0);
        s[n] = __builtin_amdgcn_mfma_f32_16x16x32_bf16(clo[kc], b8, s[n], 0, 0, 0);
      }
    }
    // ---- mask + decay, write S~ (bf16 hi) to per-wave plane (block-XOR swizzle)
#pragma unroll
    for (int n = 0; n < 2; ++n) {
      const int jg = j0 + n * 16 + fr;
      const float enj = eneg[jg];
#pragma unroll
      for (int r = 0; r < 4; ++r) {
        const int iwl = fg * 4 + r;
        const int ig = i0 + w * 16 + iwl;
        float sv = s[n][r] * eaci[r] * enj;
        sv = (jg <= ig) ? sv : 0.f;
        Sp[iwl * 32 + (((n * 2 + (fr >> 3)) ^ fg) << 3) + (fr & 7)] = (short)bf16rn(sv);
      }
    }
    // ---- PV: Y += S~ · X   (S~hi·Xhi + S~hi·Xlo)
    {
      s16x8 sa = *(const s16x8*)&Sp[fr * 32 + ((fg ^ (fr >> 2)) << 3)];
#pragma unroll
      for (int n = 0; n < 4; ++n) {
        const int drow = n * 16 + fr;
        const int px = (fg ^ ((drow >> 2) & 3)) << 3;
        s16x8 xh = *(const s16x8*)&XThi[drow * 32 + px];
        s16x8 xl = *(const s16x8*)&XTlo[drow * 32 + px];
        yacc[n] = __builtin_amdgcn_mfma_f32_16x16x32_bf16(sa, xh, yacc[n], 0, 0, 0);
        yacc[n] = __builtin_amdgcn_mfma_f32_16x16x32_bf16(sa, xl, yacc[n], 0, 0, 0);
      }
    }
    __syncthreads();
  }

  // ---- Yh = C · h_prev in two s-halves (HT half-plane aliases B planes, 16KB)
  f32x4 yh[4];
#pragma unroll
  for (int n = 0; n < 4; ++n)
#pragma unroll
    for (int r = 0; r < 4; ++r) yh[n][r] = 0.f;

#pragma unroll
  for (int m = 0; m < 2; ++m) {
    // stage h_prev^T half: h[64s][64d] -> HT[d][s_local] hi/lo
    {
      const int dd = tid & 15, tt = tid >> 4;
      F4 hr[4];
#pragma unroll
      for (int r = 0; r < 4; ++r)
        hr[r].v = *(const float4*)&Hb[(size_t)(m * 64 + tt * 4 + r) * kDH + dd * 4];
#pragma unroll
      for (int c = 0; c < 4; ++c) {
        const int d = dd * 4 + c;
        s16x4 h4, l4;
#pragma unroll
        for (int i2 = 0; i2 < 4; ++i2) {
          float x = hr[i2].f[c];
          unsigned short h = bf16rn(x);
          float hf = __uint_as_float((unsigned)h << 16);
          h4[i2] = (short)h;
          l4[i2] = (short)bf16rn(x - hf);
        }
        const int off = d * 64 + (((tt >> 1) ^ (d & 7)) << 3) + ((tt & 1) << 2);
        *(s16x4*)&HThi[off] = h4;
        *(s16x4*)&HTlo[off] = l4;
      }
    }
    __syncthreads();
#pragma unroll
    for (int kcl = 0; kcl < 2; ++kcl) {
      const int kc = m * 2 + kcl;
#pragma unroll
      for (int n = 0; n < 4; ++n) {
        const int drow = n * 16 + fr;
        const int phys = ((4 * kcl + fg) ^ (drow & 7)) * 8;
        s16x8 hh = *(const s16x8*)&HThi[drow * 64 + phys];
        s16x8 hl = *(const s16x8*)&HTlo[drow * 64 + phys];
        yh[n] = __builtin_amdgcn_mfma_f32_16x16x32_bf16(chi[kc], hh, yh[n], 0, 0, 0);
        yh[n] = __builtin_amdgcn_mfma_f32_16x16x32_bf16(chi[kc], hl, yh[n], 0, 0, 0);
        yh[n] = __builtin_amdgcn_mfma_f32_16x16x32_bf16(clo[kc], hh, yh[n], 0, 0, 0);
      }
    }
    if (m == 0) __syncthreads();  // before half-1 staging overwrites HT
  }

  // ---- epilogue: Y = (1-a)*Y_intra + a*exp(ac_i)*Yh
#pragma unroll
  for (int n = 0; n < 4; ++n) {
#pragma unroll
    for (int r = 0; r < 4; ++r) {
      const int ig = i0 + w * 16 + fg * 4 + r;
      const int d = n * 16 + fr;
      Yb[(size_t)ig * kDH + d] = (1.f - kAlpha) * yacc[n][r] + (kAlpha * eaci[r]) * yh[n][r];
    }
  }
}

// h_end[s,d] = alpha*decay_total*h_prev[s,d] + (1-alpha)*sum_t B[t,s]*w_t*X[t,d]
__global__ __launch_bounds__(256, 2) void hend_kernel(
    const float* __restrict__ Xg, const float* __restrict__ Ag,
    const float* __restrict__ Bg, const float* __restrict__ Hg,
    float* __restrict__ hend, float* __restrict__ dtot) {
  const int bh = blockIdx.x;
  const int tid = threadIdx.x;
  const float* Xb = Xg + (size_t)bh * kCS * kDH;
  const float* Ab = Ag + (size_t)bh * kCS;
  const float* Bb = Bg + (size_t)bh * kCS * kDS;
  const float* Hb = Hg + (size_t)bh * kDS * kDH;
  float* Ob = hend + (size_t)bh * kDS * kDH;

  __shared__ float ac[kCS];
  __shared__ float wsh[32];
  __shared__ float xs[32][kDH];
  __shared__ float bs[32][kDS];

  cumsum256(Ab, ac, tid);
  const float alast = ac[kCS - 1];
  if (tid == 0) dtot[bh] = __expf(alast);

  const int dcol = tid & 15;
  const int srow = tid >> 4;
  float4 acc[8];
#pragma unroll
  for (int m = 0; m < 8; ++m) acc[m] = make_float4(0.f, 0.f, 0.f, 0.f);

  for (int t0 = 0; t0 < kCS; t0 += 32) {
    __syncthreads();
    if (tid < 32) wsh[tid] = __expf(alast - ac[t0 + tid]);
    __syncthreads();
#pragma unroll
    for (int k = 0; k < 2; ++k) {
      int fid = k * 256 + tid;
      int r = fid >> 4, c = fid & 15;
      float4 xv = *(const float4*)&Xb[(size_t)(t0 + r) * kDH + c * 4];
      float wv = wsh[r];
      xv.x *= wv; xv.y *= wv; xv.z *= wv; xv.w *= wv;
      *(float4*)&xs[r][c * 4] = xv;
    }
#pragma unroll
    for (int k = 0; k < 4; ++k) {
      int fid = k * 256 + tid;
      int r = fid >> 5, c = fid & 31;
      *(float4*)&bs[r][c * 4] = *(const float4*)&Bb[(size_t)(t0 + r) * kDS + c * 4];
    }
    __syncthreads();
    for (int tt = 0; tt < 32; ++tt) {
      float4 xv = *(const float4*)&xs[tt][dcol * 4];
#pragma unroll
      for (int m = 0; m < 8; ++m) {
        float b = bs[tt][srow + 16 * m];
        acc[m].x = fmaf(b, xv.x, acc[m].x);
        acc[m].y = fmaf(b, xv.y, acc[m].y);
        acc[m].z = fmaf(b, xv.z, acc[m].z);
        acc[m].w = fmaf(b, xv.w, acc[m].w);
      }
    }
  }
  const float dscale = kAlpha * __expf(alast);
  const float sc = 1.f - kAlpha;
#pragma unroll
  for (int m = 0; m < 8; ++m) {
    int s = srow + 16 * m;
    float4 hv = *(const float4*)&Hb[(size_t)s * kDH + dcol * 4];
    float4 o;
    o.x = dscale * hv.x + sc * acc[m].x;
    o.y = dscale * hv.y + sc * acc[m].y;
    o.z = dscale * hv.z + sc * acc[m].z;
    o.w = dscale * hv.w + sc * acc[m].w;
    *(float4*)&Ob[(size_t)s * kDH + dcol * 4] = o;
  }
}

extern "C" void kernel_launch(void* const* d_in, const int* in_sizes, int n_in,
                              void* d_out, int out_size, void* d_ws, size_t ws_size,
                              hipStream_t stream) {
  const float* X = (const float*)d_in[0];
  const float* A = (const float*)d_in[1];
  const float* B = (const float*)d_in[2];
  const float* C = (const float*)d_in[3];
  const float* H = (const float*)d_in[4];
  float* out = (float*)d_out;
  float* Y = out;
  float* hend = Y + (size_t)kBH * kCS * kDH;
  float* dt = hend + (size_t)kBH * kDS * kDH;

  y_mfma_kernel<<<2048, 256, 0, stream>>>(X, A, B, C, H, Y);
  hend_kernel<<<kBH, 256, 0, stream>>>(X, A, B, H, hend, dt);
}